// Round 13
// baseline (410.749 us; speedup 1.0000x reference)
//
#include <hip/hip_runtime.h>
#include <hip/hip_cooperative_groups.h>
#include <cstdint>

namespace cg = cooperative_groups;

#define B_   512
#define I_   2560
#define H_   512
#define E_   300
#define EW   320     // padded emb width
#define V_   8000
#define VPAD 8064    // 63 * 128
#define T_   16
#define G4H  2048
#define SOS_ 2

typedef _Float16 f16;
typedef _Float16 f16x8 __attribute__((ext_vector_type(8)));
typedef _Float16 f16x4 __attribute__((ext_vector_type(4)));
typedef float    f32x4 __attribute__((ext_vector_type(4)));

__device__ __forceinline__ float sigmoidf_(float x) {
    return 1.0f / (1.0f + __expf(-x));
}

__device__ __forceinline__ void gload16(const void* g, void* l) {
    __builtin_amdgcn_global_load_lds(
        (const __attribute__((address_space(1))) void*)g,
        (__attribute__((address_space(3))) void*)l,
        16, 0, 0);
}

// ---------------------------------------------------------------------------
// MFMA f16 GEMM (m97 structure) writing f16 C (+f32 bias) — ctxg producer.
// ---------------------------------------------------------------------------
__global__ __launch_bounds__(256)
void gemm_mfma_f16o(const f16* __restrict__ A, int lda,
                    const f16* __restrict__ Bw, int ldb,
                    f16* __restrict__ C, int ldc,
                    int K,
                    const float* __restrict__ bias1)
{
    __shared__ f16 As[128][32];
    __shared__ f16 Bs[128][32];

    const int tid  = threadIdx.x;
    const int w    = tid >> 6;
    const int lane = tid & 63;
    const int bm   = blockIdx.x * 128;
    const int bn   = blockIdx.y * 128;
    const int wr   = w >> 1;
    const int wc   = w & 1;

    const int srow = lane >> 2;
    const int skel = (lane & 3) * 8;

    const f16* Ag0 = A  + (size_t)(bm + w*32 +      srow) * lda + skel;
    const f16* Ag1 = A  + (size_t)(bm + w*32 + 16 + srow) * lda + skel;
    const f16* Bg0 = Bw + (size_t)(bn + w*32 +      srow) * ldb + skel;
    const f16* Bg1 = Bw + (size_t)(bn + w*32 + 16 + srow) * ldb + skel;
    f16* Al0 = &As[w*32     ][0];
    f16* Al1 = &As[w*32 + 16][0];
    f16* Bl0 = &Bs[w*32     ][0];
    f16* Bl1 = &Bs[w*32 + 16][0];

    const int frow = lane & 15;
    const int fk   = (lane >> 4) * 8;

    f32x4 acc[4][4] = {};

    for (int k0 = 0; k0 < K; k0 += 32) {
        gload16(Ag0 + k0, Al0);
        gload16(Ag1 + k0, Al1);
        gload16(Bg0 + k0, Bl0);
        gload16(Bg1 + k0, Bl1);
        __syncthreads();

        f16x8 af[4], bf[4];
        #pragma unroll
        for (int m = 0; m < 4; ++m)
            af[m] = *reinterpret_cast<const f16x8*>(&As[wr*64 + m*16 + frow][fk]);
        #pragma unroll
        for (int n = 0; n < 4; ++n)
            bf[n] = *reinterpret_cast<const f16x8*>(&Bs[wc*64 + n*16 + frow][fk]);

        #pragma unroll
        for (int m = 0; m < 4; ++m)
            #pragma unroll
            for (int n = 0; n < 4; ++n)
                acc[m][n] = __builtin_amdgcn_mfma_f32_16x16x32_f16(
                    af[m], bf[n], acc[m][n], 0, 0, 0);

        __syncthreads();
    }

    const int rowb = bm + wr*64 + (lane >> 4) * 4;
    #pragma unroll
    for (int n = 0; n < 4; ++n) {
        const int col = bn + wc*64 + n*16 + frow;
        const float badd = bias1 ? bias1[col] : 0.0f;
        #pragma unroll
        for (int m = 0; m < 4; ++m) {
            const int r0 = rowb + m*16;
            #pragma unroll
            for (int r = 0; r < 4; ++r)
                C[(size_t)(r0 + r) * ldc + col] = (f16)(acc[m][n][r] + badd);
        }
    }
}

// ---------------------------------------------------------------------------
// ctx/cell-init GEMM (verified round 9/11/12).
// ---------------------------------------------------------------------------
__global__ __launch_bounds__(256)
void gemm_ctx_init(const f16* __restrict__ A,
                   const f16* __restrict__ Bw,
                   const float* __restrict__ b_in,
                   const float* __restrict__ b_cell,
                   f16* __restrict__ ctx16,
                   f16* __restrict__ h0, f16* __restrict__ h1,
                   float* __restrict__ c0, float* __restrict__ c1)
{
    __shared__ f16 As[128][32];
    __shared__ f16 Bs[128][32];

    const int tid  = threadIdx.x;
    const int w    = tid >> 6;
    const int lane = tid & 63;
    const int bm   = blockIdx.x * 128;
    const int bn   = blockIdx.y * 128;
    const int wr   = w >> 1;
    const int wc   = w & 1;

    const int srow = lane >> 2;
    const int skel = (lane & 3) * 8;

    const f16* Ag0 = A  + (size_t)(bm + w*32 +      srow) * I_ + skel;
    const f16* Ag1 = A  + (size_t)(bm + w*32 + 16 + srow) * I_ + skel;
    const f16* Bg0 = Bw + (size_t)(bn + w*32 +      srow) * I_ + skel;
    const f16* Bg1 = Bw + (size_t)(bn + w*32 + 16 + srow) * I_ + skel;
    f16* Al0 = &As[w*32     ][0];
    f16* Al1 = &As[w*32 + 16][0];
    f16* Bl0 = &Bs[w*32     ][0];
    f16* Bl1 = &Bs[w*32 + 16][0];

    const int frow = lane & 15;
    const int fk   = (lane >> 4) * 8;

    f32x4 acc[4][4] = {};

    for (int k0 = 0; k0 < I_; k0 += 32) {
        gload16(Ag0 + k0, Al0);
        gload16(Ag1 + k0, Al1);
        gload16(Bg0 + k0, Bl0);
        gload16(Bg1 + k0, Bl1);
        __syncthreads();

        f16x8 af[4], bf[4];
        #pragma unroll
        for (int m = 0; m < 4; ++m)
            af[m] = *reinterpret_cast<const f16x8*>(&As[wr*64 + m*16 + frow][fk]);
        #pragma unroll
        for (int n = 0; n < 4; ++n)
            bf[n] = *reinterpret_cast<const f16x8*>(&Bs[wc*64 + n*16 + frow][fk]);

        #pragma unroll
        for (int m = 0; m < 4; ++m)
            #pragma unroll
            for (int n = 0; n < 4; ++n)
                acc[m][n] = __builtin_amdgcn_mfma_f32_16x16x32_f16(
                    af[m], bf[n], acc[m][n], 0, 0, 0);

        __syncthreads();
    }

    const int rowb = bm + wr*64 + (lane >> 4) * 4;
    #pragma unroll
    for (int n = 0; n < 4; ++n) {
        const int col = bn + wc*64 + n*16 + frow;
        #pragma unroll
        for (int m = 0; m < 4; ++m) {
            const int r0 = rowb + m*16;
            #pragma unroll
            for (int r = 0; r < 4; ++r) {
                const int row = r0 + r;
                if (col < 512) {
                    const f16 ch = (f16)(acc[m][n][r] + b_in[col]);
                    ctx16[(size_t)row * 512 + col] = ch;
                    h0[(size_t)row * 512 + col] = ch;
                    h1[(size_t)row * 512 + col] = ch;
                } else {
                    const float cc = acc[m][n][r] + b_cell[col - 512];
                    c0[(size_t)row * 512 + col - 512] = cc;
                    c1[(size_t)row * 512 + col - 512] = cc;
                }
            }
        }
    }
}

// ---------------------------------------------------------------------------
// Recurrent GEMM + fused LSTM cell body (round-12 verified, byte-identical).
// Single-barrier NB=3/D=2 pipeline, steady vmcnt(6). LDS 72 KB.
// ---------------------------------------------------------------------------
__device__ __forceinline__ void gemm_cell_body(
    const f16* __restrict__ Ap1, const f16* __restrict__ Ap2, int lda2,
    const f16* __restrict__ Wp, int K,
    const f16* __restrict__ Cadd,
    const float* __restrict__ bih, const float* __restrict__ bhh,
    float* __restrict__ cst,
    f16* __restrict__ hout1,
    char* smem, int bm, int bn)
{
    const int tid  = threadIdx.x;
    const int w    = tid >> 6;
    const int lane = tid & 63;
    const int wr   = w >> 1, wc = w & 1;
    const int frow = lane & 15, hi = lane >> 4;
    const int sw   = (frow & 7) << 4;
    const int srow8 = lane >> 3;
    const int ksb  = ((((lane & 7) * 16) ^ (srow8 << 4)) >> 1);

    const int NT = K >> 6;
    f32x4 acc[2][4] = {};

    char* Abuf = smem;            // 3 x 8192
    char* Wbuf = smem + 24576;    // 3 x 16384

    auto stage = [&](int bsel, int kt) {
        const int k0 = kt << 6;
        #pragma unroll
        for (int j = 0; j < 2; ++j) {
            const int row = w*16 + j*8 + srow8;
            const f16* src;
            if (k0 < 512) src = Ap1 + (size_t)(bm + row) * 512  + k0 + ksb;
            else          src = Ap2 + (size_t)(bm + row) * lda2 + (k0 - 512) + ksb;
            gload16(src, Abuf + bsel*8192 + (w*2 + j)*1024 + lane*16);
        }
        #pragma unroll
        for (int j = 0; j < 4; ++j) {
            const int row = w*32 + j*8 + srow8;
            gload16(Wp + (size_t)(bn + row) * K + k0 + ksb,
                    Wbuf + bsel*16384 + (w*4 + j)*1024 + lane*16);
        }
    };

    stage(0, 0);
    stage(1, 1);

    int rb = 0;
    for (int kt = 0; kt < NT; ++kt) {
        if (kt < NT - 1) asm volatile("s_waitcnt vmcnt(6)" ::: "memory");
        else             asm volatile("s_waitcnt vmcnt(0)" ::: "memory");
        __builtin_amdgcn_sched_barrier(0);
        __builtin_amdgcn_s_barrier();
        __builtin_amdgcn_sched_barrier(0);

        const char* A_ = Abuf + rb*8192;
        const char* W_ = Wbuf + rb*16384;
        f16x8 af[2][2], bf[2][4];
        #pragma unroll
        for (int ks = 0; ks < 2; ++ks) {
            const int cb = (ks*64 + hi*16) ^ sw;
            #pragma unroll
            for (int m = 0; m < 2; ++m)
                af[ks][m] = *reinterpret_cast<const f16x8*>(A_ + (wr*32 + m*16 + frow)*128 + cb);
            #pragma unroll
            for (int n = 0; n < 4; ++n)
                bf[ks][n] = *reinterpret_cast<const f16x8*>(W_ + (wc*64 + n*16 + frow)*128 + cb);
        }

        if (kt + 2 < NT) {
            int sb = rb - 1; if (sb < 0) sb = 2;
            stage(sb, kt + 2);
        }

        #pragma unroll
        for (int ks = 0; ks < 2; ++ks)
            #pragma unroll
            for (int m = 0; m < 2; ++m)
                #pragma unroll
                for (int n = 0; n < 4; ++n)
                    acc[m][n] = __builtin_amdgcn_mfma_f32_16x16x32_f16(
                        af[ks][m], bf[ks][n], acc[m][n], 0, 0, 0);
        rb = (rb == 2) ? 0 : rb + 1;
    }
    __syncthreads();

    float* gs = (float*)smem;
    #pragma unroll
    for (int m = 0; m < 2; ++m) {
        const int row = wr*32 + m*16 + hi*4;
        #pragma unroll
        for (int n = 0; n < 4; ++n) {
            const int col = wc*64 + n*16 + frow;
            #pragma unroll
            for (int r = 0; r < 4; ++r) {
                float v = acc[m][n][r];
                if (Cadd) v += (float)Cadd[(size_t)(bm + row + r) * G4H + bn + col];
                gs[(row + r)*132 + col] = v;
            }
        }
    }
    __syncthreads();

    const int hp = tid & 31;
    const int hg = (bn >> 2) + hp;
    float bi0 = 0.f, bi1 = 0.f, bi2 = 0.f, bi3 = 0.f;
    if (bih) {
        bi0 = bih[hg]        + bhh[hg];
        bi1 = bih[512 + hg]  + bhh[512 + hg];
        bi2 = bih[1024 + hg] + bhh[1024 + hg];
        bi3 = bih[1536 + hg] + bhh[1536 + hg];
    }
    #pragma unroll
    for (int i = 0; i < 8; ++i) {
        const int r = (tid >> 5) * 8 + i;
        const int b = bm + r;
        const float gi = gs[r*132 +      hp] + bi0;
        const float gf = gs[r*132 + 32 + hp] + bi1;
        const float gc = gs[r*132 + 64 + hp] + bi2;
        const float go = gs[r*132 + 96 + hp] + bi3;
        const float c  = cst[(size_t)b * 512 + hg];
        const float cn = sigmoidf_(gf) * c + sigmoidf_(gi) * tanhf(gc);
        const float hn = sigmoidf_(go) * tanhf(cn);
        cst[(size_t)b * 512 + hg] = cn;
        hout1[(size_t)b * 512 + hg] = (f16)hn;
    }
    __syncthreads();     // gs reads done before smem reuse next phase
}

// ---------------------------------------------------------------------------
// Output-projection tile body (round-9/11/12 verified).
// ---------------------------------------------------------------------------
__device__ __forceinline__ void gemm_out_body(
    const f16* __restrict__ A, const f16* __restrict__ Bw,
    float* __restrict__ C,     // = out + t*V_
    const float* __restrict__ bias,
    int bm, int bn, char* smem, int tid)
{
    const int w    = tid >> 6;
    const int lane = tid & 63;
    const int wr   = w >> 1, wc = w & 1;
    const int frow = lane & 15, hi = lane >> 4;
    const int sw   = (frow & 7) << 4;
    const int srow8 = lane >> 3;
    const int ksb  = ((((lane & 7) * 16) ^ (srow8 << 4)) >> 1);

    char* Abuf = smem;            // 2 x 16384
    char* Wbuf = smem + 32768;    // 2 x 16384
    f32x4 acc[4][4] = {};

    auto stage = [&](int bsel, int kt) {
        const int k0 = kt << 6;
        #pragma unroll
        for (int j = 0; j < 4; ++j) {
            const int row = w*32 + j*8 + srow8;
            gload16(A  + (size_t)(bm + row) * 512 + k0 + ksb,
                    Abuf + bsel*16384 + (w*4 + j)*1024 + lane*16);
            gload16(Bw + (size_t)(bn + row) * 512 + k0 + ksb,
                    Wbuf + bsel*16384 + (w*4 + j)*1024 + lane*16);
        }
    };

    stage(0, 0);
    stage(1, 1);

    int buf = 0;
    for (int kt = 0; kt < 8; ++kt) {
        if (kt < 7) asm volatile("s_waitcnt vmcnt(8)" ::: "memory");
        else        asm volatile("s_waitcnt vmcnt(0)" ::: "memory");
        __builtin_amdgcn_sched_barrier(0);
        __builtin_amdgcn_s_barrier();
        __builtin_amdgcn_sched_barrier(0);

        const char* A_ = Abuf + buf*16384;
        const char* W_ = Wbuf + buf*16384;
        f16x8 af[2][4], bf[2][4];
        #pragma unroll
        for (int ks = 0; ks < 2; ++ks) {
            const int cb = (ks*64 + hi*16) ^ sw;
            #pragma unroll
            for (int m = 0; m < 4; ++m)
                af[ks][m] = *reinterpret_cast<const f16x8*>(A_ + (wr*64 + m*16 + frow)*128 + cb);
            #pragma unroll
            for (int n = 0; n < 4; ++n)
                bf[ks][n] = *reinterpret_cast<const f16x8*>(W_ + (wc*64 + n*16 + frow)*128 + cb);
        }
        __builtin_amdgcn_sched_barrier(0);
        asm volatile("s_waitcnt lgkmcnt(0)" ::: "memory");
        __builtin_amdgcn_sched_barrier(0);
        __builtin_amdgcn_s_barrier();
        __builtin_amdgcn_sched_barrier(0);

        if (kt + 2 < 8) stage(buf, kt + 2);

        #pragma unroll
        for (int ks = 0; ks < 2; ++ks)
            #pragma unroll
            for (int m = 0; m < 4; ++m)
                #pragma unroll
                for (int n = 0; n < 4; ++n)
                    acc[m][n] = __builtin_amdgcn_mfma_f32_16x16x32_f16(
                        af[ks][m], bf[ks][n], acc[m][n], 0, 0, 0);
        buf ^= 1;
    }

    const int rowb = bm + wr*64 + (lane >> 4) * 4;
    #pragma unroll
    for (int n = 0; n < 4; ++n) {
        const int col = bn + wc*64 + n*16 + frow;
        if (col >= V_) continue;
        const float badd = bias[col];
        #pragma unroll
        for (int m = 0; m < 4; ++m) {
            const int r0 = rowb + m*16;
            #pragma unroll
            for (int r = 0; r < 4; ++r)
                __builtin_nontemporal_store(
                    acc[m][n][r] + badd,
                    &C[(size_t)(r0 + r) * (T_ * V_) + col]);
        }
    }
    __syncthreads();
}

// ---------------------------------------------------------------------------
// PERSISTENT cooperative kernel: 512 blocks, roles fixed across 18 phases,
// grid.sync() between phases (17 syncs). Buffer parity identical to the
// verified multi-launch schedule. Dispatch tax paid once.
// ---------------------------------------------------------------------------
struct PersistArgs {
    const f16* embAll;
    const f16* W0p; const f16* W1p; const f16* WoutP;
    const f16* ctxg;
    const float* bih1; const float* bhh1; const float* b_out;
    float* c0; float* c1;
    f16* h0a; f16* h0b; f16* h1a; f16* h1b;
    float* out;
};

__global__ __launch_bounds__(256, 2)
void lstm_persist(PersistArgs a)
{
    __shared__ char smem[73728];
    cg::grid_group grid = cg::this_grid();
    const int bx = blockIdx.x;
    const int tid = threadIdx.x;

    f16* h0buf[2] = { a.h0a, a.h0b };
    f16* h1buf[2] = { a.h1a, a.h1b };

    for (int p = 0; p <= T_ + 1; ++p) {
        if (bx < 128) {
            if (p < T_) {
                const int xcd = bx & 7, idx = bx >> 3;
                const int bn = (xcd*2 + (idx & 1)) * 128;
                const int bm = (idx >> 1) * 64;
                gemm_cell_body(h0buf[(p + 1) & 1],
                               a.embAll + (size_t)p * B_ * EW, EW,
                               a.W0p, 832, a.ctxg, nullptr, nullptr,
                               a.c0, h0buf[p & 1], smem, bm, bn);
            }
        } else if (bx < 256) {
            if (p >= 1 && p <= T_) {
                const int lb = bx - 128;
                const int xcd = lb & 7, idx = lb >> 3;
                const int bn = (xcd*2 + (idx & 1)) * 128;
                const int bm = (idx >> 1) * 64;
                gemm_cell_body(h0buf[(p + 1) & 1],
                               h1buf[p & 1], 512,
                               a.W1p, 1024, nullptr, a.bih1, a.bhh1,
                               a.c1, h1buf[(p + 1) & 1], smem, bm, bn);
            }
        } else {
            if (p >= 2) {
                const int o = bx - 256;              // 0..255
                const int xcd = o & 7, j = o >> 3;   // j 0..31
                const int bnt = xcd*8 + (j >> 2);    // 0..63
                const int bm = (j & 3) * 128;
                if (bnt < 63)
                    gemm_out_body(h1buf[p & 1], a.WoutP,
                                  a.out + (size_t)(p - 2) * V_, a.b_out,
                                  bm, bnt * 128, smem, tid);
            }
        }
        if (p < T_ + 1) grid.sync();
    }
}

// ---------------------------------------------------------------------------
// Fallback multi-launch phase kernel (round-12 verified).
// ---------------------------------------------------------------------------
__global__ __launch_bounds__(256)
void phase_kernel(const f16* __restrict__ h0in,
                  const f16* __restrict__ embt,
                  f16* __restrict__ h0out,
                  const f16* __restrict__ h1in,
                  f16* __restrict__ h1out,
                  const f16* __restrict__ W0p, const f16* __restrict__ W1p,
                  const f16* __restrict__ WoutP,
                  const f16* __restrict__ ctxg,
                  const float* __restrict__ bih1, const float* __restrict__ bhh1,
                  const float* __restrict__ b_out,
                  float* __restrict__ c0, float* __restrict__ c1,
                  float* __restrict__ out, int tout,
                  int bx0, int active0, int active1, int activeO)
{
    __shared__ char smem[73728];
    const int bx = blockIdx.x + bx0;

    if (bx < 128) {
        if (!active0) return;
        const int xcd = bx & 7, idx = bx >> 3;
        const int bn = (xcd*2 + (idx & 1)) * 128;
        const int bm = (idx >> 1) * 64;
        gemm_cell_body(h0in, embt, EW, W0p, 832,
                       ctxg, nullptr, nullptr, c0, h0out, smem, bm, bn);
    } else if (bx < 256) {
        if (!active1) return;
        const int lb = bx - 128;
        const int xcd = lb & 7, idx = lb >> 3;
        const int bn = (xcd*2 + (idx & 1)) * 128;
        const int bm = (idx >> 1) * 64;
        gemm_cell_body(h0in, h1in, 512, W1p, 1024,
                       nullptr, bih1, bhh1, c1, h1out, smem, bm, bn);
    } else {
        if (!activeO) return;
        const int o = bx - 256;
        const int xcd = o & 7, j = o >> 3;
        const int bnt = xcd*8 + (j >> 2);
        if (bnt >= 63) return;
        const int bm = (j & 3) * 128;
        gemm_out_body(h1in, WoutP, out + (size_t)tout * V_, b_out,
                      bm, bnt * 128, smem, threadIdx.x);
    }
}

// ---------------------------------------------------------------------------
// ONE merged setup kernel, float4-vectorized (round-12 verified).
// ---------------------------------------------------------------------------
#define NB_F16   1280
#define NB_WIC   2560
#define NB_W0    1664
#define NB_W1    2048
#define NB_WCTX  1024
#define NB_B0    8
#define NB_WOUT  4032
#define NB_EMB   2560
#define NB_TOTAL (NB_F16+NB_WIC+NB_W0+NB_W1+NB_WCTX+NB_B0+NB_WOUT+NB_EMB)

__global__ __launch_bounds__(256)
void pack_all(const float* __restrict__ fused,
              const float* __restrict__ Win, const float* __restrict__ Wcell,
              const float* __restrict__ Whh0, const float* __restrict__ Wih0,
              const float* __restrict__ Wih1, const float* __restrict__ Whh1,
              const float* __restrict__ bih0, const float* __restrict__ bhh0,
              const float* __restrict__ Wout,
              const float* __restrict__ emb, const int* __restrict__ target,
              f16* __restrict__ fused16, f16* __restrict__ WinCell,
              f16* __restrict__ W0, f16* __restrict__ W1,
              f16* __restrict__ Wc, float* __restrict__ b01p,
              f16* __restrict__ Wo, f16* __restrict__ embAll)
{
    int bx = blockIdx.x;
    const int tid = threadIdx.x;

    auto cvt4 = [](float4 v) {
        return f16x4{ (f16)v.x, (f16)v.y, (f16)v.z, (f16)v.w };
    };

    if (bx < NB_F16) {
        const int i = bx * 256 + tid;
        *reinterpret_cast<f16x4*>(fused16 + (size_t)i * 4) =
            cvt4(reinterpret_cast<const float4*>(fused)[i]);
        return;
    }
    bx -= NB_F16;
    if (bx < NB_WIC) {
        const int i = bx * 256 + tid;
        const int r = i / 640, c4 = (i % 640) * 4;
        const float* src = (r < 512) ? Win + (size_t)r * I_ + c4
                                     : Wcell + (size_t)(r - 512) * I_ + c4;
        *reinterpret_cast<f16x4*>(WinCell + (size_t)i * 4) =
            cvt4(*reinterpret_cast<const float4*>(src));
        return;
    }
    bx -= NB_WIC;
    if (bx < NB_W0) {
        const int idx = bx * 256 + tid;
        const int rp = idx / 208, k = (idx % 208) * 4;
        const int g = (rp >> 5) & 3, h = (rp >> 7) * 32 + (rp & 31);
        const int srow = g * 512 + h;
        f16x4 o = { (f16)0.f, (f16)0.f, (f16)0.f, (f16)0.f };
        if (k < 512)
            o = cvt4(*reinterpret_cast<const float4*>(Whh0 + (size_t)srow * 512 + k));
        else if (k < 812)
            o = cvt4(*reinterpret_cast<const float4*>(Wih0 + (size_t)srow * 812 + (k - 512)));
        *reinterpret_cast<f16x4*>(W0 + (size_t)rp * 832 + k) = o;
        return;
    }
    bx -= NB_W0;
    if (bx < NB_W1) {
        const int idx = bx * 256 + tid;
        const int rp = idx >> 8, k = (idx & 255) * 4;
        const int g = (rp >> 5) & 3, h = (rp >> 7) * 32 + (rp & 31);
        const int srow = g * 512 + h;
        const float* src = (k < 512) ? Wih1 + (size_t)srow * 512 + k
                                     : Whh1 + (size_t)srow * 512 + (k - 512);
        *reinterpret_cast<f16x4*>(W1 + (size_t)rp * 1024 + k) =
            cvt4(*reinterpret_cast<const float4*>(src));
        return;
    }
    bx -= NB_W1;
    if (bx < NB_WCTX) {
        const int idx = bx * 256 + tid;
        const int rp = idx >> 7, k = (idx & 127) * 4;
        const int g = (rp >> 5) & 3, h = (rp >> 7) * 32 + (rp & 31);
        *reinterpret_cast<f16x4*>(Wc + (size_t)rp * 512 + k) =
            cvt4(*reinterpret_cast<const float4*>(
                Wih0 + (size_t)(g * 512 + h) * 812 + 300 + k));
        return;
    }
    bx -= NB_WCTX;
    if (bx < NB_B0) {
        const int idx = bx * 256 + tid;
        const int g = (idx >> 5) & 3, h = (idx >> 7) * 32 + (idx & 31);
        b01p[idx] = bih0[g * 512 + h] + bhh0[g * 512 + h];
        return;
    }
    bx -= NB_B0;
    if (bx < NB_WOUT) {
        const int i = bx * 256 + tid;
        const int r = i >> 7, c4 = (i & 127) * 4;
        f16x4 o = { (f16)0.f, (f16)0.f, (f16)0.f, (f16)0.f };
        if (r < V_)
            o = cvt4(*reinterpret_cast<const float4*>(Wout + (size_t)r * H_ + c4));
        *reinterpret_cast<f16x4*>(Wo + (size_t)i * 4) = o;
        return;
    }
    bx -= NB_WOUT;
    {
        const int idx = bx * 256 + tid;
        const int t = idx / (B_ * 80);
        const int rem = idx % (B_ * 80);
        const int b = rem / 80, e = (rem % 80) * 4;
        const int wd = (t == 0) ? SOS_ : target[b * T_ + (t - 1)];
        f16x4 o = { (f16)0.f, (f16)0.f, (f16)0.f, (f16)0.f };
        if (e < E_)
            o = cvt4(*reinterpret_cast<const float4*>(emb + (size_t)wd * E_ + e));
        *reinterpret_cast<f16x4*>(embAll + ((size_t)t * B_ + b) * EW + e) = o;
    }
}

// ---------------------------------------------------------------------------
extern "C" void kernel_launch(void* const* d_in, const int* in_sizes, int n_in,
                              void* d_out, int out_size, void* d_ws, size_t ws_size,
                              hipStream_t stream)
{
    const float* fused  = (const float*)d_in[0];
    const int*   target = (const int*)d_in[1];
    const float* emb    = (const float*)d_in[3];
    const float* W_in   = (const float*)d_in[4];
    const float* b_in   = (const float*)d_in[5];
    const float* W_cell = (const float*)d_in[6];
    const float* b_cell = (const float*)d_in[7];
    const float* W_ih0  = (const float*)d_in[8];
    const float* W_hh0  = (const float*)d_in[9];
    const float* b_ih0  = (const float*)d_in[10];
    const float* b_hh0  = (const float*)d_in[11];
    const float* W_ih1  = (const float*)d_in[12];
    const float* W_hh1  = (const float*)d_in[13];
    const float* b_ih1  = (const float*)d_in[14];
    const float* b_hh1  = (const float*)d_in[15];
    const float* W_out  = (const float*)d_in[16];
    const float* b_out  = (const float*)d_in[17];
    float* out = (float*)d_out;

    char* p = (char*)d_ws;
    auto carve = [&](size_t bytes) {
        char* r = p;
        p += (bytes + 255) & ~(size_t)255;
        return r;
    };
    f16* ctxg     = (f16*)carve((size_t)B_ * G4H * 2);
    float* b01p   = (float*)carve((size_t)G4H * 4);
    float* c0     = (float*)carve((size_t)B_ * H_ * 4);
    float* c1     = (float*)carve((size_t)B_ * H_ * 4);
    f16* fused16  = (f16*)carve((size_t)B_ * I_ * 2);
    f16* WinCell  = (f16*)carve((size_t)1024 * I_ * 2);
    f16* W0p      = (f16*)carve((size_t)G4H * 832 * 2);
    f16* W1p      = (f16*)carve((size_t)G4H * 1024 * 2);
    f16* Wctxp    = (f16*)carve((size_t)G4H * H_ * 2);
    f16* Wout16   = (f16*)carve((size_t)VPAD * H_ * 2);
    f16* ctx16    = (f16*)carve((size_t)B_ * H_ * 2);
    f16* h0a      = (f16*)carve((size_t)B_ * H_ * 2);
    f16* h0b      = (f16*)carve((size_t)B_ * H_ * 2);
    f16* h1a      = (f16*)carve((size_t)B_ * H_ * 2);
    f16* h1b      = (f16*)carve((size_t)B_ * H_ * 2);
    f16* embAll   = (f16*)carve((size_t)T_ * B_ * EW * 2);

    // ---- 1 merged pack launch ----
    pack_all<<<dim3(NB_TOTAL), 256, 0, stream>>>(
        fused, W_in, W_cell, W_hh0, W_ih0, W_ih1, W_hh1,
        b_ih0, b_hh0, W_out, emb, target,
        fused16, WinCell, W0p, W1p, Wctxp, b01p, Wout16, embAll);

    // ---- ctx/cell-init GEMM with fused init epilogue ----
    gemm_ctx_init<<<dim3(B_/128, 1024/128), 256, 0, stream>>>(
        fused16, WinCell, b_in, b_cell, ctx16, h0b, h1b, c0, c1);

    // ---- time-invariant ctx gate contribution (+ b0 biases), f16 out ----
    gemm_mfma_f16o<<<dim3(B_/128, G4H/128), 256, 0, stream>>>(
        ctx16, H_, Wctxp, H_, ctxg, G4H, H_, b01p);

    // ---- recurrent + out-projection: persistent cooperative if possible ----
    PersistArgs pa;
    pa.embAll = embAll; pa.W0p = W0p; pa.W1p = W1p; pa.WoutP = Wout16;
    pa.ctxg = ctxg; pa.bih1 = b_ih1; pa.bhh1 = b_hh1; pa.b_out = b_out;
    pa.c0 = c0; pa.c1 = c1;
    pa.h0a = h0a; pa.h0b = h0b; pa.h1a = h1a; pa.h1b = h1b;
    pa.out = out;

    int maxBlk = 0;
    hipError_t qerr = hipOccupancyMaxActiveBlocksPerMultiprocessor(
        &maxBlk, (const void*)lstm_persist, 256, 0);
    bool usePersist = (qerr == hipSuccess && maxBlk >= 2);

    if (usePersist) {
        void* kargs[] = { (void*)&pa };
        hipError_t lerr = hipLaunchCooperativeKernel(
            (const void*)lstm_persist, dim3(512), dim3(256), kargs, 0, stream);
        usePersist = (lerr == hipSuccess);
    }

    if (!usePersist) {
        // fallback: verified 18-launch skewed schedule (round 12)
        f16* h0buf[2] = { h0a, h0b };
        f16* h1buf[2] = { h1a, h1b };
        for (int phase = 0; phase <= T_ + 1; ++phase) {
            const int a0 = (phase < T_) ? 1 : 0;
            const int a1 = (phase >= 1 && phase <= T_) ? 1 : 0;
            const int aO = (phase >= 2) ? 1 : 0;
            const int te = (phase < T_) ? phase : (T_ - 1);
            const int tO = aO ? (phase - 2) : 0;
            int bx0 = 0, nb = 512;
            if (phase == 0)            { bx0 = 0;   nb = 128; }
            else if (phase == 1)       { bx0 = 0;   nb = 256; }
            else if (phase == T_)      { bx0 = 128; nb = 384; }
            else if (phase == T_ + 1)  { bx0 = 256; nb = 256; }
            phase_kernel<<<dim3(nb), 256, 0, stream>>>(
                h0buf[(phase + 1) & 1],
                embAll + (size_t)te * B_ * EW,
                h0buf[phase & 1],
                h1buf[phase & 1],
                h1buf[(phase + 1) & 1],
                W0p, W1p, Wout16, ctxg, b_ih1, b_hh1, b_out,
                c0, c1, out, tO, bx0, a0, a1, aO);
        }
    }
}

// Round 14
// 409.457 us; speedup vs baseline: 1.0032x; 1.0032x over previous
//
#include <hip/hip_runtime.h>
#include <cstdint>

#define B_   512
#define I_   2560
#define H_   512
#define E_   300
#define EW   320     // padded emb width
#define V_   8000
#define VPAD 8064    // 63 * 128
#define T_   16
#define G4H  2048
#define SOS_ 2

typedef _Float16 f16;
typedef _Float16 f16x8 __attribute__((ext_vector_type(8)));
typedef _Float16 f16x4 __attribute__((ext_vector_type(4)));
typedef float    f32x4 __attribute__((ext_vector_type(4)));

__device__ __forceinline__ float sigmoidf_(float x) {
    return 1.0f / (1.0f + __expf(-x));
}

__device__ __forceinline__ void gload16(const void* g, void* l) {
    __builtin_amdgcn_global_load_lds(
        (const __attribute__((address_space(1))) void*)g,
        (__attribute__((address_space(3))) void*)l,
        16, 0, 0);
}

// ---------------------------------------------------------------------------
// MFMA f16 GEMM (m97 structure) writing f16 C (+f32 bias) — ctxg producer.
// ---------------------------------------------------------------------------
__global__ __launch_bounds__(256)
void gemm_mfma_f16o(const f16* __restrict__ A, int lda,
                    const f16* __restrict__ Bw, int ldb,
                    f16* __restrict__ C, int ldc,
                    int K,
                    const float* __restrict__ bias1)
{
    __shared__ f16 As[128][32];
    __shared__ f16 Bs[128][32];

    const int tid  = threadIdx.x;
    const int w    = tid >> 6;
    const int lane = tid & 63;
    const int bm   = blockIdx.x * 128;
    const int bn   = blockIdx.y * 128;
    const int wr   = w >> 1;
    const int wc   = w & 1;

    const int srow = lane >> 2;
    const int skel = (lane & 3) * 8;

    const f16* Ag0 = A  + (size_t)(bm + w*32 +      srow) * lda + skel;
    const f16* Ag1 = A  + (size_t)(bm + w*32 + 16 + srow) * lda + skel;
    const f16* Bg0 = Bw + (size_t)(bn + w*32 +      srow) * ldb + skel;
    const f16* Bg1 = Bw + (size_t)(bn + w*32 + 16 + srow) * ldb + skel;
    f16* Al0 = &As[w*32     ][0];
    f16* Al1 = &As[w*32 + 16][0];
    f16* Bl0 = &Bs[w*32     ][0];
    f16* Bl1 = &Bs[w*32 + 16][0];

    const int frow = lane & 15;
    const int fk   = (lane >> 4) * 8;

    f32x4 acc[4][4] = {};

    for (int k0 = 0; k0 < K; k0 += 32) {
        gload16(Ag0 + k0, Al0);
        gload16(Ag1 + k0, Al1);
        gload16(Bg0 + k0, Bl0);
        gload16(Bg1 + k0, Bl1);
        __syncthreads();

        f16x8 af[4], bf[4];
        #pragma unroll
        for (int m = 0; m < 4; ++m)
            af[m] = *reinterpret_cast<const f16x8*>(&As[wr*64 + m*16 + frow][fk]);
        #pragma unroll
        for (int n = 0; n < 4; ++n)
            bf[n] = *reinterpret_cast<const f16x8*>(&Bs[wc*64 + n*16 + frow][fk]);

        #pragma unroll
        for (int m = 0; m < 4; ++m)
            #pragma unroll
            for (int n = 0; n < 4; ++n)
                acc[m][n] = __builtin_amdgcn_mfma_f32_16x16x32_f16(
                    af[m], bf[n], acc[m][n], 0, 0, 0);

        __syncthreads();
    }

    const int rowb = bm + wr*64 + (lane >> 4) * 4;
    #pragma unroll
    for (int n = 0; n < 4; ++n) {
        const int col = bn + wc*64 + n*16 + frow;
        const float badd = bias1 ? bias1[col] : 0.0f;
        #pragma unroll
        for (int m = 0; m < 4; ++m) {
            const int r0 = rowb + m*16;
            #pragma unroll
            for (int r = 0; r < 4; ++r)
                C[(size_t)(r0 + r) * ldc + col] = (f16)(acc[m][n][r] + badd);
        }
    }
}

// ---------------------------------------------------------------------------
// ctx/cell-init GEMM (verified round 9/11/12).
// ---------------------------------------------------------------------------
__global__ __launch_bounds__(256)
void gemm_ctx_init(const f16* __restrict__ A,
                   const f16* __restrict__ Bw,
                   const float* __restrict__ b_in,
                   const float* __restrict__ b_cell,
                   f16* __restrict__ ctx16,
                   f16* __restrict__ h0, f16* __restrict__ h1,
                   float* __restrict__ c0, float* __restrict__ c1)
{
    __shared__ f16 As[128][32];
    __shared__ f16 Bs[128][32];

    const int tid  = threadIdx.x;
    const int w    = tid >> 6;
    const int lane = tid & 63;
    const int bm   = blockIdx.x * 128;
    const int bn   = blockIdx.y * 128;
    const int wr   = w >> 1;
    const int wc   = w & 1;

    const int srow = lane >> 2;
    const int skel = (lane & 3) * 8;

    const f16* Ag0 = A  + (size_t)(bm + w*32 +      srow) * I_ + skel;
    const f16* Ag1 = A  + (size_t)(bm + w*32 + 16 + srow) * I_ + skel;
    const f16* Bg0 = Bw + (size_t)(bn + w*32 +      srow) * I_ + skel;
    const f16* Bg1 = Bw + (size_t)(bn + w*32 + 16 + srow) * I_ + skel;
    f16* Al0 = &As[w*32     ][0];
    f16* Al1 = &As[w*32 + 16][0];
    f16* Bl0 = &Bs[w*32     ][0];
    f16* Bl1 = &Bs[w*32 + 16][0];

    const int frow = lane & 15;
    const int fk   = (lane >> 4) * 8;

    f32x4 acc[4][4] = {};

    for (int k0 = 0; k0 < I_; k0 += 32) {
        gload16(Ag0 + k0, Al0);
        gload16(Ag1 + k0, Al1);
        gload16(Bg0 + k0, Bl0);
        gload16(Bg1 + k0, Bl1);
        __syncthreads();

        f16x8 af[4], bf[4];
        #pragma unroll
        for (int m = 0; m < 4; ++m)
            af[m] = *reinterpret_cast<const f16x8*>(&As[wr*64 + m*16 + frow][fk]);
        #pragma unroll
        for (int n = 0; n < 4; ++n)
            bf[n] = *reinterpret_cast<const f16x8*>(&Bs[wc*64 + n*16 + frow][fk]);

        #pragma unroll
        for (int m = 0; m < 4; ++m)
            #pragma unroll
            for (int n = 0; n < 4; ++n)
                acc[m][n] = __builtin_amdgcn_mfma_f32_16x16x32_f16(
                    af[m], bf[n], acc[m][n], 0, 0, 0);

        __syncthreads();
    }

    const int rowb = bm + wr*64 + (lane >> 4) * 4;
    #pragma unroll
    for (int n = 0; n < 4; ++n) {
        const int col = bn + wc*64 + n*16 + frow;
        #pragma unroll
        for (int m = 0; m < 4; ++m) {
            const int r0 = rowb + m*16;
            #pragma unroll
            for (int r = 0; r < 4; ++r) {
                const int row = r0 + r;
                if (col < 512) {
                    const f16 ch = (f16)(acc[m][n][r] + b_in[col]);
                    ctx16[(size_t)row * 512 + col] = ch;
                    h0[(size_t)row * 512 + col] = ch;
                    h1[(size_t)row * 512 + col] = ch;
                } else {
                    const float cc = acc[m][n][r] + b_cell[col - 512];
                    c0[(size_t)row * 512 + col - 512] = cc;
                    c1[(size_t)row * 512 + col - 512] = cc;
                }
            }
        }
    }
}

// ---------------------------------------------------------------------------
// Recurrent GEMM + fused LSTM cell body: SINGLE-BARRIER pipeline (round 12).
// NB=3 buffers, issue-distance D=2 => NB >= D+1, so the post-read barrier is
// provably unnecessary. LDS: Abuf 3x8K @0, Wbuf 3x16K @24K (72 KB).
// Steady s_waitcnt vmcnt(6).
// ---------------------------------------------------------------------------
__device__ __forceinline__ void gemm_cell_body(
    const f16* __restrict__ Ap1, const f16* __restrict__ Ap2, int lda2,
    const f16* __restrict__ Wp, int K,
    const f16* __restrict__ Cadd,
    const float* __restrict__ bih, const float* __restrict__ bhh,
    float* __restrict__ cst,
    f16* __restrict__ hout1,
    char* smem, int bm, int bn)
{
    const int tid  = threadIdx.x;
    const int w    = tid >> 6;
    const int lane = tid & 63;
    const int wr   = w >> 1, wc = w & 1;
    const int frow = lane & 15, hi = lane >> 4;
    const int sw   = (frow & 7) << 4;
    const int srow8 = lane >> 3;
    const int ksb  = ((((lane & 7) * 16) ^ (srow8 << 4)) >> 1);

    const int NT = K >> 6;
    f32x4 acc[2][4] = {};

    char* Abuf = smem;            // 3 x 8192
    char* Wbuf = smem + 24576;    // 3 x 16384

    auto stage = [&](int bsel, int kt) {
        const int k0 = kt << 6;
        #pragma unroll
        for (int j = 0; j < 2; ++j) {
            const int row = w*16 + j*8 + srow8;
            const f16* src;
            if (k0 < 512) src = Ap1 + (size_t)(bm + row) * 512  + k0 + ksb;
            else          src = Ap2 + (size_t)(bm + row) * lda2 + (k0 - 512) + ksb;
            gload16(src, Abuf + bsel*8192 + (w*2 + j)*1024 + lane*16);
        }
        #pragma unroll
        for (int j = 0; j < 4; ++j) {
            const int row = w*32 + j*8 + srow8;
            gload16(Wp + (size_t)(bn + row) * K + k0 + ksb,
                    Wbuf + bsel*16384 + (w*4 + j)*1024 + lane*16);
        }
    };

    stage(0, 0);
    stage(1, 1);

    int rb = 0;                                  // read buffer = kt % 3
    for (int kt = 0; kt < NT; ++kt) {
        if (kt < NT - 1) asm volatile("s_waitcnt vmcnt(6)" ::: "memory");
        else             asm volatile("s_waitcnt vmcnt(0)" ::: "memory");
        __builtin_amdgcn_sched_barrier(0);
        __builtin_amdgcn_s_barrier();            // tile kt visible to all
        __builtin_amdgcn_sched_barrier(0);       // pin stage below the barrier

        const char* A_ = Abuf + rb*8192;
        const char* W_ = Wbuf + rb*16384;
        f16x8 af[2][2], bf[2][4];
        #pragma unroll
        for (int ks = 0; ks < 2; ++ks) {
            const int cb = (ks*64 + hi*16) ^ sw;
            #pragma unroll
            for (int m = 0; m < 2; ++m)
                af[ks][m] = *reinterpret_cast<const f16x8*>(A_ + (wr*32 + m*16 + frow)*128 + cb);
            #pragma unroll
            for (int n = 0; n < 4; ++n)
                bf[ks][n] = *reinterpret_cast<const f16x8*>(W_ + (wc*64 + n*16 + frow)*128 + cb);
        }

        if (kt + 2 < NT) {
            int sb = rb - 1; if (sb < 0) sb = 2;   // (rb+2)%3
            stage(sb, kt + 2);
        }

        #pragma unroll
        for (int ks = 0; ks < 2; ++ks)
            #pragma unroll
            for (int m = 0; m < 2; ++m)
                #pragma unroll
                for (int n = 0; n < 4; ++n)
                    acc[m][n] = __builtin_amdgcn_mfma_f32_16x16x32_f16(
                        af[ks][m], bf[ks][n], acc[m][n], 0, 0, 0);
        rb = (rb == 2) ? 0 : rb + 1;
    }
    __syncthreads();               // all waves done with LDS bufs -> alias gs

    // gates -> LDS (+ Cadd f16), f32 [64][132]
    float* gs = (float*)smem;
    #pragma unroll
    for (int m = 0; m < 2; ++m) {
        const int row = wr*32 + m*16 + hi*4;
        #pragma unroll
        for (int n = 0; n < 4; ++n) {
            const int col = wc*64 + n*16 + frow;
            #pragma unroll
            for (int r = 0; r < 4; ++r) {
                float v = acc[m][n][r];
                if (Cadd) v += (float)Cadd[(size_t)(bm + row + r) * G4H + bn + col];
                gs[(row + r)*132 + col] = v;
            }
        }
    }
    __syncthreads();

    const int hp = tid & 31;
    const int hg = (bn >> 2) + hp;
    float bi0 = 0.f, bi1 = 0.f, bi2 = 0.f, bi3 = 0.f;
    if (bih) {
        bi0 = bih[hg]        + bhh[hg];
        bi1 = bih[512 + hg]  + bhh[512 + hg];
        bi2 = bih[1024 + hg] + bhh[1024 + hg];
        bi3 = bih[1536 + hg] + bhh[1536 + hg];
    }
    #pragma unroll
    for (int i = 0; i < 8; ++i) {
        const int r = (tid >> 5) * 8 + i;
        const int b = bm + r;
        const float gi = gs[r*132 +      hp] + bi0;
        const float gf = gs[r*132 + 32 + hp] + bi1;
        const float gc = gs[r*132 + 64 + hp] + bi2;
        const float go = gs[r*132 + 96 + hp] + bi3;
        const float c  = cst[(size_t)b * 512 + hg];
        const float cn = sigmoidf_(gf) * c + sigmoidf_(gi) * tanhf(gc);
        const float hn = sigmoidf_(go) * tanhf(cn);
        cst[(size_t)b * 512 + hg] = cn;
        hout1[(size_t)b * 512 + hg] = (f16)hn;
    }
}

// ---------------------------------------------------------------------------
// Output-projection tile body (round-9/11/12 verified): BK=64, XOR-swizzled,
// depth-2 counted vmcnt, nontemporal C stores. LDS: A 2x16K @0, W 2x16K @32K.
// ---------------------------------------------------------------------------
__device__ __forceinline__ void gemm_out_body(
    const f16* __restrict__ A, const f16* __restrict__ Bw,
    float* __restrict__ C,     // = out + t*V_
    const float* __restrict__ bias,
    int bm, int bn, char* smem, int tid)
{
    const int w    = tid >> 6;
    const int lane = tid & 63;
    const int wr   = w >> 1, wc = w & 1;
    const int frow = lane & 15, hi = lane >> 4;
    const int sw   = (frow & 7) << 4;
    const int srow8 = lane >> 3;
    const int ksb  = ((((lane & 7) * 16) ^ (srow8 << 4)) >> 1);

    char* Abuf = smem;            // 2 x 16384
    char* Wbuf = smem + 32768;    // 2 x 16384
    f32x4 acc[4][4] = {};

    auto stage = [&](int bsel, int kt) {
        const int k0 = kt << 6;
        #pragma unroll
        for (int j = 0; j < 4; ++j) {
            const int row = w*32 + j*8 + srow8;
            gload16(A  + (size_t)(bm + row) * 512 + k0 + ksb,
                    Abuf + bsel*16384 + (w*4 + j)*1024 + lane*16);
            gload16(Bw + (size_t)(bn + row) * 512 + k0 + ksb,
                    Wbuf + bsel*16384 + (w*4 + j)*1024 + lane*16);
        }
    };

    stage(0, 0);
    stage(1, 1);

    int buf = 0;
    for (int kt = 0; kt < 8; ++kt) {
        if (kt < 7) asm volatile("s_waitcnt vmcnt(8)" ::: "memory");
        else        asm volatile("s_waitcnt vmcnt(0)" ::: "memory");
        __builtin_amdgcn_sched_barrier(0);
        __builtin_amdgcn_s_barrier();
        __builtin_amdgcn_sched_barrier(0);

        const char* A_ = Abuf + buf*16384;
        const char* W_ = Wbuf + buf*16384;
        f16x8 af[2][4], bf[2][4];
        #pragma unroll
        for (int ks = 0; ks < 2; ++ks) {
            const int cb = (ks*64 + hi*16) ^ sw;
            #pragma unroll
            for (int m = 0; m < 4; ++m)
                af[ks][m] = *reinterpret_cast<const f16x8*>(A_ + (wr*64 + m*16 + frow)*128 + cb);
            #pragma unroll
            for (int n = 0; n < 4; ++n)
                bf[ks][n] = *reinterpret_cast<const f16x8*>(W_ + (wc*64 + n*16 + frow)*128 + cb);
        }
        __builtin_amdgcn_sched_barrier(0);
        asm volatile("s_waitcnt lgkmcnt(0)" ::: "memory");
        __builtin_amdgcn_sched_barrier(0);
        __builtin_amdgcn_s_barrier();
        __builtin_amdgcn_sched_barrier(0);

        if (kt + 2 < 8) stage(buf, kt + 2);

        #pragma unroll
        for (int ks = 0; ks < 2; ++ks)
            #pragma unroll
            for (int m = 0; m < 4; ++m)
                #pragma unroll
                for (int n = 0; n < 4; ++n)
                    acc[m][n] = __builtin_amdgcn_mfma_f32_16x16x32_f16(
                        af[ks][m], bf[ks][n], acc[m][n], 0, 0, 0);
        buf ^= 1;
    }

    const int rowb = bm + wr*64 + (lane >> 4) * 4;
    #pragma unroll
    for (int n = 0; n < 4; ++n) {
        const int col = bn + wc*64 + n*16 + frow;
        if (col >= V_) continue;
        const float badd = bias[col];
        #pragma unroll
        for (int m = 0; m < 4; ++m) {
            const int r0 = rowb + m*16;
            #pragma unroll
            for (int r = 0; r < 4; ++r)
                __builtin_nontemporal_store(
                    acc[m][n][r] + badd,
                    &C[(size_t)(r0 + r) * (T_ * V_) + col]);
        }
    }
}

// ---------------------------------------------------------------------------
// Fused phase kernel: logical blocks [0,128) L0, [128,256) L1, [256,512) OUT;
// bx0 trims inactive head/tail ranges. 72 KB LDS -> 2 blocks/CU.
// XCD-aware bn ownership (round 8/9 verified).
// NOTE (rounds 4/5/13): persistent-kernel variants of this schedule are
// 3-6x SLOWER on MI355X — grid-wide sync (coop grid.sync or hand-rolled
// device-scope barrier) costs ~35-90us each due to per-XCD L2 invalidation
// + cold refetch. Dependent stream launches (~15us each) are the fastest
// cross-XCD synchronization primitive available. Do not revisit.
// ---------------------------------------------------------------------------
__global__ __launch_bounds__(256)
void phase_kernel(const f16* __restrict__ h0in,
                  const f16* __restrict__ embt,
                  f16* __restrict__ h0out,
                  const f16* __restrict__ h1in,
                  f16* __restrict__ h1out,
                  const f16* __restrict__ W0p, const f16* __restrict__ W1p,
                  const f16* __restrict__ WoutP,
                  const f16* __restrict__ ctxg,
                  const float* __restrict__ bih1, const float* __restrict__ bhh1,
                  const float* __restrict__ b_out,
                  float* __restrict__ c0, float* __restrict__ c1,
                  float* __restrict__ out, int tout,
                  int bx0, int active0, int active1, int activeO)
{
    __shared__ char smem[73728];
    const int bx = blockIdx.x + bx0;

    if (bx < 128) {
        if (!active0) return;
        const int xcd = bx & 7, idx = bx >> 3;
        const int bn = (xcd*2 + (idx & 1)) * 128;
        const int bm = (idx >> 1) * 64;
        gemm_cell_body(h0in, embt, EW, W0p, 832,
                       ctxg, nullptr, nullptr, c0, h0out, smem, bm, bn);
    } else if (bx < 256) {
        if (!active1) return;
        const int lb = bx - 128;
        const int xcd = lb & 7, idx = lb >> 3;
        const int bn = (xcd*2 + (idx & 1)) * 128;
        const int bm = (idx >> 1) * 64;
        gemm_cell_body(h0in, h1in, 512, W1p, 1024,
                       nullptr, bih1, bhh1, c1, h1out, smem, bm, bn);
    } else {
        if (!activeO) return;
        const int o = bx - 256;                  // 0..255
        const int xcd = o & 7, j = o >> 3;       // j 0..31
        const int bnt = xcd*8 + (j >> 2);        // 0..63
        if (bnt >= 63) return;                   // 4 idle blocks
        const int bm = (j & 3) * 128;
        gemm_out_body(h1in, WoutP, out + (size_t)tout * V_, b_out,
                      bm, bnt * 128, smem, threadIdx.x);
    }
}

// ---------------------------------------------------------------------------
// ONE merged setup kernel, float4-vectorized segments (round-12 verified).
// ---------------------------------------------------------------------------
#define NB_F16   1280                 // fused16: 512*2560/4/256
#define NB_WIC   2560                 // WinCell: 1024*2560/4/256
#define NB_W0    1664                 // W0p: 2048*208/256
#define NB_W1    2048                 // W1p: 2048*256/256
#define NB_WCTX  1024                 // Wctxp: 2048*128/256
#define NB_B0    8
#define NB_WOUT  4032                 // Wout16: 8064*128/256
#define NB_EMB   2560                 // embAll: 16*512*80/256
#define NB_TOTAL (NB_F16+NB_WIC+NB_W0+NB_W1+NB_WCTX+NB_B0+NB_WOUT+NB_EMB)

__global__ __launch_bounds__(256)
void pack_all(const float* __restrict__ fused,
              const float* __restrict__ Win, const float* __restrict__ Wcell,
              const float* __restrict__ Whh0, const float* __restrict__ Wih0,
              const float* __restrict__ Wih1, const float* __restrict__ Whh1,
              const float* __restrict__ bih0, const float* __restrict__ bhh0,
              const float* __restrict__ Wout,
              const float* __restrict__ emb, const int* __restrict__ target,
              f16* __restrict__ fused16, f16* __restrict__ WinCell,
              f16* __restrict__ W0, f16* __restrict__ W1,
              f16* __restrict__ Wc, float* __restrict__ b01p,
              f16* __restrict__ Wo, f16* __restrict__ embAll)
{
    int bx = blockIdx.x;
    const int tid = threadIdx.x;

    auto cvt4 = [](float4 v) {
        return f16x4{ (f16)v.x, (f16)v.y, (f16)v.z, (f16)v.w };
    };

    if (bx < NB_F16) {
        const int i = bx * 256 + tid;
        *reinterpret_cast<f16x4*>(fused16 + (size_t)i * 4) =
            cvt4(reinterpret_cast<const float4*>(fused)[i]);
        return;
    }
    bx -= NB_F16;
    if (bx < NB_WIC) {
        const int i = bx * 256 + tid;
        const int r = i / 640, c4 = (i % 640) * 4;
        const float* src = (r < 512) ? Win + (size_t)r * I_ + c4
                                     : Wcell + (size_t)(r - 512) * I_ + c4;
        *reinterpret_cast<f16x4*>(WinCell + (size_t)i * 4) =
            cvt4(*reinterpret_cast<const float4*>(src));
        return;
    }
    bx -= NB_WIC;
    if (bx < NB_W0) {
        const int idx = bx * 256 + tid;       // 2048*208
        const int rp = idx / 208, k = (idx % 208) * 4;
        const int g = (rp >> 5) & 3, h = (rp >> 7) * 32 + (rp & 31);
        const int srow = g * 512 + h;
        f16x4 o = { (f16)0.f, (f16)0.f, (f16)0.f, (f16)0.f };
        if (k < 512)
            o = cvt4(*reinterpret_cast<const float4*>(Whh0 + (size_t)srow * 512 + k));
        else if (k < 812)
            o = cvt4(*reinterpret_cast<const float4*>(Wih0 + (size_t)srow * 812 + (k - 512)));
        *reinterpret_cast<f16x4*>(W0 + (size_t)rp * 832 + k) = o;
        return;
    }
    bx -= NB_W0;
    if (bx < NB_W1) {
        const int idx = bx * 256 + tid;       // 2048*256
        const int rp = idx >> 8, k = (idx & 255) * 4;
        const int g = (rp >> 5) & 3, h = (rp >> 7) * 32 + (rp & 31);
        const int srow = g * 512 + h;
        const float* src = (k < 512) ? Wih1 + (size_t)srow * 512 + k
                                     : Whh1 + (size_t)srow * 512 + (k - 512);
        *reinterpret_cast<f16x4*>(W1 + (size_t)rp * 1024 + k) =
            cvt4(*reinterpret_cast<const float4*>(src));
        return;
    }
    bx -= NB_W1;
    if (bx < NB_WCTX) {
        const int idx = bx * 256 + tid;       // 2048*128
        const int rp = idx >> 7, k = (idx & 127) * 4;
        const int g = (rp >> 5) & 3, h = (rp >> 7) * 32 + (rp & 31);
        *reinterpret_cast<f16x4*>(Wc + (size_t)rp * 512 + k) =
            cvt4(*reinterpret_cast<const float4*>(
                Wih0 + (size_t)(g * 512 + h) * 812 + 300 + k));
        return;
    }
    bx -= NB_WCTX;
    if (bx < NB_B0) {
        const int idx = bx * 256 + tid;
        const int g = (idx >> 5) & 3, h = (idx >> 7) * 32 + (idx & 31);
        b01p[idx] = bih0[g * 512 + h] + bhh0[g * 512 + h];
        return;
    }
    bx -= NB_B0;
    if (bx < NB_WOUT) {
        const int i = bx * 256 + tid;
        const int r = i >> 7, c4 = (i & 127) * 4;
        f16x4 o = { (f16)0.f, (f16)0.f, (f16)0.f, (f16)0.f };
        if (r < V_)
            o = cvt4(*reinterpret_cast<const float4*>(Wout + (size_t)r * H_ + c4));
        *reinterpret_cast<f16x4*>(Wo + (size_t)i * 4) = o;
        return;
    }
    bx -= NB_WOUT;
    {
        const int idx = bx * 256 + tid;       // 16*512*80
        const int t = idx / (B_ * 80);
        const int rem = idx % (B_ * 80);
        const int b = rem / 80, e = (rem % 80) * 4;
        const int wd = (t == 0) ? SOS_ : target[b * T_ + (t - 1)];
        f16x4 o = { (f16)0.f, (f16)0.f, (f16)0.f, (f16)0.f };
        if (e < E_)
            o = cvt4(*reinterpret_cast<const float4*>(emb + (size_t)wd * E_ + e));
        *reinterpret_cast<f16x4*>(embAll + ((size_t)t * B_ + b) * EW + e) = o;
    }
}

// ---------------------------------------------------------------------------
extern "C" void kernel_launch(void* const* d_in, const int* in_sizes, int n_in,
                              void* d_out, int out_size, void* d_ws, size_t ws_size,
                              hipStream_t stream)
{
    const float* fused  = (const float*)d_in[0];
    const int*   target = (const int*)d_in[1];
    const float* emb    = (const float*)d_in[3];
    const float* W_in   = (const float*)d_in[4];
    const float* b_in   = (const float*)d_in[5];
    const float* W_cell = (const float*)d_in[6];
    const float* b_cell = (const float*)d_in[7];
    const float* W_ih0  = (const float*)d_in[8];
    const float* W_hh0  = (const float*)d_in[9];
    const float* b_ih0  = (const float*)d_in[10];
    const float* b_hh0  = (const float*)d_in[11];
    const float* W_ih1  = (const float*)d_in[12];
    const float* W_hh1  = (const float*)d_in[13];
    const float* b_ih1  = (const float*)d_in[14];
    const float* b_hh1  = (const float*)d_in[15];
    const float* W_out  = (const float*)d_in[16];
    const float* b_out  = (const float*)d_in[17];
    float* out = (float*)d_out;

    char* p = (char*)d_ws;
    auto carve = [&](size_t bytes) {
        char* r = p;
        p += (bytes + 255) & ~(size_t)255;
        return r;
    };
    f16* ctxg     = (f16*)carve((size_t)B_ * G4H * 2);
    float* b01p   = (float*)carve((size_t)G4H * 4);
    float* c0     = (float*)carve((size_t)B_ * H_ * 4);
    float* c1     = (float*)carve((size_t)B_ * H_ * 4);
    f16* fused16  = (f16*)carve((size_t)B_ * I_ * 2);
    f16* WinCell  = (f16*)carve((size_t)1024 * I_ * 2);
    f16* W0p      = (f16*)carve((size_t)G4H * 832 * 2);
    f16* W1p      = (f16*)carve((size_t)G4H * 1024 * 2);
    f16* Wctxp    = (f16*)carve((size_t)G4H * H_ * 2);
    f16* Wout16   = (f16*)carve((size_t)VPAD * H_ * 2);
    f16* ctx16    = (f16*)carve((size_t)B_ * H_ * 2);
    f16* h0a      = (f16*)carve((size_t)B_ * H_ * 2);
    f16* h0b      = (f16*)carve((size_t)B_ * H_ * 2);
    f16* h1a      = (f16*)carve((size_t)B_ * H_ * 2);
    f16* h1b      = (f16*)carve((size_t)B_ * H_ * 2);
    f16* embAll   = (f16*)carve((size_t)T_ * B_ * EW * 2);

    // ---- 1 merged pack launch (vectorized) ----
    pack_all<<<dim3(NB_TOTAL), 256, 0, stream>>>(
        fused, W_in, W_cell, W_hh0, W_ih0, W_ih1, W_hh1,
        b_ih0, b_hh0, W_out, emb, target,
        fused16, WinCell, W0p, W1p, Wctxp, b01p, Wout16, embAll);

    // ---- ctx/cell-init GEMM with fused init epilogue ----
    gemm_ctx_init<<<dim3(B_/128, 1024/128), 256, 0, stream>>>(
        fused16, WinCell, b_in, b_cell, ctx16, h0b, h1b, c0, c1);

    // ---- time-invariant ctx gate contribution (+ b0 biases), f16 out ----
    gemm_mfma_f16o<<<dim3(B_/128, G4H/128), 256, 0, stream>>>(
        ctx16, H_, Wctxp, H_, ctxg, G4H, H_, b01p);

    // ---- skewed recurrent + fused out-projection: phases 0..17 ----
    // Phase p: L0 -> h0(p); L1 -> h1(p-1); OUT -> logits(t = p-2).
    f16* h0buf[2] = { h0a, h0b };
    f16* h1buf[2] = { h1a, h1b };
    for (int phase = 0; phase <= T_ + 1; ++phase) {
        const int a0 = (phase < T_) ? 1 : 0;
        const int a1 = (phase >= 1 && phase <= T_) ? 1 : 0;
        const int aO = (phase >= 2) ? 1 : 0;
        const int te = (phase < T_) ? phase : (T_ - 1);
        const int tO = aO ? (phase - 2) : 0;
        int bx0 = 0, nb = 512;
        if (phase == 0)            { bx0 = 0;   nb = 128; }
        else if (phase == 1)       { bx0 = 0;   nb = 256; }
        else if (phase == T_)      { bx0 = 128; nb = 384; }   // L1 + OUT
        else if (phase == T_ + 1)  { bx0 = 256; nb = 256; }   // OUT only
        phase_kernel<<<dim3(nb), 256, 0, stream>>>(
            h0buf[(phase + 1) & 1],
            embAll + (size_t)te * B_ * EW,
            h0buf[phase & 1],
            h1buf[phase & 1],
            h1buf[(phase + 1) & 1],
            W0p, W1p, Wout16, ctxg, b_ih1, b_hh1, b_out,
            c0, c1, out, tO, bx0, a0, a1, aO);
    }
}